// Round 9
// baseline (151.140 us; speedup 1.0000x reference)
//
#include <hip/hip_runtime.h>
#include <hip/hip_bf16.h>

#define S_LEN 2048
#define E_DIM 1024
#define NH 16
#define HD 64
#define ATTN_SCALE 0.03125f                 // 1/sqrt(1024)
#define QSCALE_L2E 0.045084312f             // ATTN_SCALE * log2(e): exp2-domain softmax

typedef __attribute__((ext_vector_type(8))) short short8;
typedef __attribute__((ext_vector_type(8))) unsigned short ushort8;
typedef __attribute__((ext_vector_type(4))) unsigned short ushort4_t;
typedef __attribute__((ext_vector_type(4))) float f32x4;
typedef __attribute__((ext_vector_type(4))) float f4;
typedef __attribute__((ext_vector_type(2))) unsigned int uint2_t;

__device__ __forceinline__ float bf2f(unsigned short u) {
    unsigned int x = ((unsigned int)u) << 16;
    return __builtin_bit_cast(float, x);
}
__device__ __forceinline__ unsigned short f2bf(float f) {
    unsigned int x = __builtin_bit_cast(unsigned int, f);
    x += 0x7FFFu + ((x >> 16) & 1u);   // RNE
    return (unsigned short)(x >> 16);
}
__device__ __forceinline__ void gload16(const unsigned short* g, unsigned short* l) {
    __builtin_amdgcn_global_load_lds(
        (__attribute__((address_space(1))) void*)g,
        (__attribute__((address_space(3))) void*)l, 16, 0, 0);
}

// ---------------- x f32 -> bf16 ----------------
__global__ __launch_bounds__(256) void k_convert(const float* __restrict__ x,
                                                 unsigned short* __restrict__ xb) {
    size_t i = ((size_t)blockIdx.x * 256 + threadIdx.x) * 8;
    f4 a = *(const f4*)(x + i);
    f4 b = *(const f4*)(x + i + 4);
    ushort8 o;
    o[0] = f2bf(a[0]); o[1] = f2bf(a[1]); o[2] = f2bf(a[2]); o[3] = f2bf(a[3]);
    o[4] = f2bf(b[0]); o[5] = f2bf(b[1]); o[6] = f2bf(b[2]); o[7] = f2bf(b[3]);
    *(ushort8*)(xb + i) = o;
}

// ---------------- W f32 -> bf16 transposed (Wt[n][k] = W[k][n]) ----------------
__global__ __launch_bounds__(256) void k_transw(const float* W0, const float* W1,
                                                const float* W2, const float* W3,
                                                unsigned short* T0, unsigned short* T1,
                                                unsigned short* T2, unsigned short* T3) {
    const float* W; unsigned short* T;
    switch (blockIdx.z) {
        case 0: W = W0; T = T0; break;
        case 1: W = W1; T = T1; break;
        case 2: W = W2; T = T2; break;
        default: W = W3; T = T3; break;
    }
    __shared__ float tile[32][33];
    int tx = threadIdx.x, ty = threadIdx.y;
    int bx = blockIdx.x * 32, by = blockIdx.y * 32;
#pragma unroll
    for (int i = 0; i < 4; i++)
        tile[ty + i * 8][tx] = W[(size_t)(by + ty + i * 8) * E_DIM + bx + tx];
    __syncthreads();
#pragma unroll
    for (int i = 0; i < 4; i++)
        T[(size_t)(bx + ty + i * 8) * E_DIM + by + tx] = f2bf(tile[tx][ty + i * 8]);
}

// ---------------- RoPE cos/sin table: [2048][32] ----------------
__global__ __launch_bounds__(256) void k_rope_table(float* __restrict__ cosT,
                                                    float* __restrict__ sinT) {
    int idx = blockIdx.x * 256 + threadIdx.x;
    int s = idx >> 5, j = idx & 31;
    float inv = expf(-(float)j * (9.210340371976184f / 32.f));
    float ang = (float)s * inv;
    cosT[idx] = cosf(ang);
    sinT[idx] = sinf(ang);
}

// ---------------- bf16 GEMM: small-tile 2-phase counted-vmcnt, 3 wgs/CU ----------
// QKV3: B = [Wq;Wk;Wv] -> RoPE'd Q (scaled by ATTN_SCALE*log2e), RoPE'd K, V^T.
template <int BM, int BN, int NBN, bool QKV3>
__global__ __launch_bounds__(256, 3)
void k_gemmN(const unsigned short* __restrict__ A,
             const unsigned short* __restrict__ B,
             unsigned short* __restrict__ Qo,
             unsigned short* __restrict__ Ko,
             unsigned short* __restrict__ Vto,
             float* __restrict__ Fo,
             const float* __restrict__ cosT,
             const float* __restrict__ sinT) {
    constexpr int THREADS = 256;
    constexpr int WM = BM / 2, WN = BN / 2;
    constexpr int FM = WM / 16, FN = WN / 16;
    constexpr int NT = E_DIM / 64;
    constexpr int AR = BM * 8 / THREADS;
    constexpr int BR = BN * 8 / THREADS;
    constexpr int STG = AR + BR;
    constexpr int NWG = (4096 / BM) * NBN;
    __shared__ unsigned short Al[2][BM * 64];
    __shared__ unsigned short Bl[2][BN * 64];
    int tid = threadIdx.x, lane = tid & 63, wid = tid >> 6;
    int l15 = lane & 15, lg = lane >> 4;
    int wr = wid >> 1, wc = wid & 1;
    int orig = blockIdx.y * NBN + blockIdx.x;
    int wg = (orig & 7) * (NWG / 8) + (orig >> 3);   // bijective XCD swizzle
    int bm = wg / NBN, bn = wg % NBN;

    auto stage = [&](int buf, int k0) {
#pragma unroll
        for (int i = 0; i < AR; i++) {
            int r = i * (THREADS / 8) + wid * 8 + (lane >> 3);
            int cs = (lane & 7) ^ (r & 7);
            gload16(A + (size_t)(bm * BM + r) * E_DIM + k0 + cs * 8,
                    &Al[buf][i * (THREADS * 8) + wid * 512]);
        }
#pragma unroll
        for (int i = 0; i < BR; i++) {
            int r = i * (THREADS / 8) + wid * 8 + (lane >> 3);
            int cs = (lane & 7) ^ (r & 7);
            gload16(B + (size_t)(bn * BN + r) * E_DIM + k0 + cs * 8,
                    &Bl[buf][i * (THREADS * 8) + wid * 512]);
        }
    };

    f32x4 acc[FM][FN] = {};
    stage(0, 0);
    for (int t = 0; t < NT; t++) {
        int cur = t & 1;
        if (t + 1 < NT) {
            stage(cur ^ 1, (t + 1) * 64);
            asm volatile("s_waitcnt vmcnt(%0)" :: "n"(STG) : "memory");
        } else {
            asm volatile("s_waitcnt vmcnt(0)" ::: "memory");
        }
        __builtin_amdgcn_s_barrier();
        __builtin_amdgcn_sched_barrier(0);
#pragma unroll
        for (int ks = 0; ks < 2; ks++) {
            short8 af[FM], bfv[FN];
#pragma unroll
            for (int m = 0; m < FM; m++) {
                int r = wr * WM + m * 16 + l15;
                int gc = ks * 4 + lg;
                af[m] = *(const short8*)&Al[cur][r * 64 + ((gc ^ (r & 7)) << 3)];
            }
#pragma unroll
            for (int n = 0; n < FN; n++) {
                int r = wc * WN + n * 16 + l15;
                int gc = ks * 4 + lg;
                bfv[n] = *(const short8*)&Bl[cur][r * 64 + ((gc ^ (r & 7)) << 3)];
            }
            __builtin_amdgcn_s_setprio(1);
#pragma unroll
            for (int m = 0; m < FM; m++)
#pragma unroll
                for (int n = 0; n < FN; n++)
                    acc[m][n] = __builtin_amdgcn_mfma_f32_16x16x32_bf16(
                        af[m], bfv[n], acc[m][n], 0, 0, 0);
            __builtin_amdgcn_s_setprio(0);
        }
        __builtin_amdgcn_s_barrier();
    }
    // epilogue
#pragma unroll
    for (int m = 0; m < FM; m++) {
        int r0 = bm * BM + wr * WM + m * 16 + lg * 4;
#pragma unroll
        for (int n = 0; n < FN; n++) {
            int colg = bn * BN + wc * WN + n * 16 + l15;
            if (QKV3) {
                int z = colg >> 10, c1 = colg & 1023;
                if (z == 2) {
                    int h = c1 >> 6, d = c1 & 63;
                    int bb = r0 >> 11, s = r0 & 2047;
                    ushort4_t p;
#pragma unroll
                    for (int r = 0; r < 4; r++) p[r] = f2bf(acc[m][n][r]);
                    *(ushort4_t*)(Vto + (((size_t)((bb * 16 + h) * 64 + d)) << 11) + s) = p;
                } else {
                    // fused interleaved RoPE; Q scaled by ATTN_SCALE*log2e
                    unsigned short* T = z ? Ko : Qo;
                    int dl = c1 & 63, j = dl >> 1;
                    float sgn = (dl & 1) ? 1.f : -1.f;
                    float scq = z ? 1.f : QSCALE_L2E;
#pragma unroll
                    for (int r = 0; r < 4; r++) {
                        int row = r0 + r, s = row & 2047;
                        float c = cosT[s * 32 + j], sn = sinT[s * 32 + j];
                        float v = acc[m][n][r];
                        float p = __shfl_xor(v, 1);
                        T[(size_t)row * E_DIM + c1] = f2bf((v * c + sgn * p * sn) * scq);
                    }
                }
            } else {
#pragma unroll
                for (int r = 0; r < 4; r++)
                    Fo[(size_t)(r0 + r) * E_DIM + colg] = acc[m][n][r];
            }
        }
    }
}

// ---------------- causal flash attention v3: ring-3 prefetch, 2-wave blocks -----
// 2 waves x 16 q-rows = 32 q-rows/block; panel pair (jp, 63-jp) -> 33 KV tiles
// of 64 per block, balanced. K/V in 3-deep LDS ring, prefetch 2 tiles ahead,
// counted vmcnt(8) (never drained in loop). 3 blocks/CU (52.5KB LDS).
// exp2-domain softmax (log2e folded into Q), defer-max (THR=8), cvt_pk P->bf16.
__global__ __launch_bounds__(128, 2) void k_attn(const unsigned short* __restrict__ Q,
                                                 const unsigned short* __restrict__ K,
                                                 const unsigned short* __restrict__ Vt,
                                                 unsigned short* __restrict__ O) {
    __shared__ unsigned short K_lds[3][64 * 64];
    __shared__ unsigned short V_lds[3][64 * 64];
    __shared__ unsigned short P_lds[2][16][72];
    int tid = threadIdx.x, lane = tid & 63, wid = tid >> 6;
    int l15 = lane & 15, lg = lane >> 4;
    int orig = blockIdx.y * 32 + blockIdx.x;         // 1024 wgs
    int wg = (orig & 7) * 128 + (orig >> 3);         // XCD swizzle: 4 bh per XCD
    int jp = wg & 31, bh = wg >> 5;
    int b = bh >> 4, h = bh & 15;
    const size_t base_qk = (size_t)b * S_LEN * E_DIM + (size_t)h * HD;
    const unsigned short* Vbh = Vt + ((size_t)(bh * 64) << 11);

    auto stageK = [&](int buf, int kt) {       // 64 k-rows x 64 d (8KB)
#pragma unroll
        for (int i = 0; i < 4; i++) {
            int r = i * 16 + wid * 8 + (lane >> 3);
            int cs = (lane & 7) ^ (r & 7);
            gload16(K + base_qk + (size_t)(kt * 64 + r) * E_DIM + cs * 8,
                    &K_lds[buf][i * 1024 + wid * 512]);
        }
    };
    auto stageV = [&](int buf, int kt) {       // 64 d-rows x 64 k (8KB)
#pragma unroll
        for (int i = 0; i < 4; i++) {
            int r = i * 16 + wid * 8 + (lane >> 3);
            int cs = (lane & 7) ^ (r & 7);
            gload16(Vbh + (size_t)r * 2048 + kt * 64 + cs * 8,
                    &V_lds[buf][i * 1024 + wid * 512]);
        }
    };

    for (int pass = 0; pass < 2; ++pass) {
        int p = pass ? (63 - jp) : jp;         // q-panel of 32 rows
        const unsigned short* Qb = Q + base_qk + (size_t)(p * 32 + wid * 16) * E_DIM;
        short8 bq[2];
#pragma unroll
        for (int s2 = 0; s2 < 2; s2++)
            bq[s2] = *(const short8*)(Qb + (size_t)l15 * E_DIM + s2 * 32 + lg * 8);
        f32x4 acc_o[4] = {};
        float m_i = -1e30f, l_i = 0.f;
        int q_glob = p * 32 + wid * 16 + l15;
        int nkt = (p + 2) >> 1;                // KV tiles of 64
        __builtin_amdgcn_s_barrier();          // prev pass done reading LDS
        stageK(0, 0);
        stageV(0, 0);
        if (nkt > 1) {
            stageK(1, 1);
            stageV(1, 1);
            asm volatile("s_waitcnt vmcnt(8)" ::: "memory");   // tile 0 landed
        } else {
            asm volatile("s_waitcnt vmcnt(0)" ::: "memory");
        }
        __builtin_amdgcn_s_barrier();
        __builtin_amdgcn_sched_barrier(0);
        for (int kt = 0; kt < nkt; ++kt) {
            int cur = kt % 3;
            if (kt + 2 < nkt) {                // prefetch 2 ahead
                stageK((kt + 2) % 3, kt + 2);
                stageV((kt + 2) % 3, kt + 2);
            }
            // S^T = K . Q^T (exp2 domain; scale*log2e pre-folded into Q)
            f32x4 acc_s[4] = {};
            __builtin_amdgcn_s_setprio(1);
#pragma unroll
            for (int mf = 0; mf < 4; mf++) {
                int rK = mf * 16 + l15;
#pragma unroll
                for (int s2 = 0; s2 < 2; s2++) {
                    int gc = s2 * 4 + lg;
                    short8 a = *(const short8*)
                        &K_lds[cur][rK * 64 + ((gc ^ (rK & 7)) << 3)];
                    acc_s[mf] = __builtin_amdgcn_mfma_f32_16x16x32_bf16(
                        a, bq[s2], acc_s[mf], 0, 0, 0);
                }
            }
            __builtin_amdgcn_s_setprio(0);
            // softmax over 16 lane-local scores (q = l15)
            float sv[16];
            float vmax = -1e30f;
            if (kt == nkt - 1) {
#pragma unroll
                for (int mf = 0; mf < 4; mf++)
#pragma unroll
                    for (int r = 0; r < 4; r++) {
                        int kg = kt * 64 + mf * 16 + lg * 4 + r;
                        float v = acc_s[mf][r];
                        if (kg > q_glob) v = -1e30f;
                        sv[mf * 4 + r] = v;
                        vmax = fmaxf(vmax, v);
                    }
            } else {
#pragma unroll
                for (int mf = 0; mf < 4; mf++)
#pragma unroll
                    for (int r = 0; r < 4; r++) {
                        float v = acc_s[mf][r];
                        sv[mf * 4 + r] = v;
                        vmax = fmaxf(vmax, v);
                    }
            }
            vmax = fmaxf(vmax, __shfl_xor(vmax, 16));
            vmax = fmaxf(vmax, __shfl_xor(vmax, 32));
            // defer-max (T13): rescale only when tile max grew by > 8 (exp2 dom.)
            if (!__all(vmax - m_i <= 8.0f)) {
                float m_new = fmaxf(m_i, vmax);
                float corr = exp2f(m_i - m_new);
                l_i *= corr;
#pragma unroll
                for (int r = 0; r < 4; r++) {
                    float c4 = __shfl(corr, lg * 4 + r);
#pragma unroll
                    for (int nf = 0; nf < 4; nf++) acc_o[nf][r] *= c4;
                }
                m_i = m_new;
            }
            float rowsum = 0.f;
#pragma unroll
            for (int i = 0; i < 16; i++) {
                float pv = exp2f(sv[i] - m_i);
                sv[i] = pv;
                rowsum += pv;
            }
            rowsum += __shfl_xor(rowsum, 16);
            rowsum += __shfl_xor(rowsum, 32);
            l_i += rowsum;
            // P -> bf16 via cvt_pk, wave-private LDS [q][k]
#pragma unroll
            for (int mf = 0; mf < 4; mf++) {
                unsigned int w0, w1;
                asm("v_cvt_pk_bf16_f32 %0, %1, %2"
                    : "=v"(w0) : "v"(sv[mf * 4 + 0]), "v"(sv[mf * 4 + 1]));
                asm("v_cvt_pk_bf16_f32 %0, %1, %2"
                    : "=v"(w1) : "v"(sv[mf * 4 + 2]), "v"(sv[mf * 4 + 3]));
                uint2_t w; w[0] = w0; w[1] = w1;
                *(uint2_t*)&P_lds[wid][l15][mf * 16 + lg * 4] = w;
            }
            // PV: O += P . V
            __builtin_amdgcn_s_setprio(1);
#pragma unroll
            for (int s2 = 0; s2 < 2; s2++) {
                short8 pa = *(const short8*)&P_lds[wid][l15][s2 * 32 + lg * 8];
#pragma unroll
                for (int nf = 0; nf < 4; nf++) {
                    int rV = nf * 16 + l15;
                    int gc = s2 * 4 + lg;
                    short8 bv = *(const short8*)
                        &V_lds[cur][rV * 64 + ((gc ^ (rV & 7)) << 3)];
                    acc_o[nf] = __builtin_amdgcn_mfma_f32_16x16x32_bf16(
                        pa, bv, acc_o[nf], 0, 0, 0);
                }
            }
            __builtin_amdgcn_s_setprio(0);
            if (kt + 1 < nkt) {
                if (kt + 2 < nkt)
                    asm volatile("s_waitcnt vmcnt(8)" ::: "memory");  // t+1 landed
                else
                    asm volatile("s_waitcnt vmcnt(0)" ::: "memory");
                __builtin_amdgcn_s_barrier();
                __builtin_amdgcn_sched_barrier(0);
            }
        }
        unsigned short* Ob = O + base_qk + (size_t)(p * 32 + wid * 16) * E_DIM;
#pragma unroll
        for (int r = 0; r < 4; r++) {
            float linv = 1.f / __shfl(l_i, lg * 4 + r);
#pragma unroll
            for (int nf = 0; nf < 4; nf++)
                Ob[(size_t)(lg * 4 + r) * E_DIM + nf * 16 + l15] =
                    f2bf(acc_o[nf][r] * linv);
        }
    }
}

extern "C" void kernel_launch(void* const* d_in, const int* in_sizes, int n_in,
                              void* d_out, int out_size, void* d_ws, size_t ws_size,
                              hipStream_t stream) {
    (void)in_sizes; (void)n_in; (void)out_size; (void)ws_size;
    const float* x  = (const float*)d_in[0];
    const float* Wq = (const float*)d_in[1];
    const float* Wk = (const float*)d_in[2];
    const float* Wv = (const float*)d_in[3];
    const float* Wo = (const float*)d_in[4];

    unsigned short* us = (unsigned short*)d_ws;
    unsigned short* xb    = us;                  // 4096x1024
    unsigned short* WqkvT = us + 4194304;        // 3072x1024 (Wq;Wk;Wv rows)
    unsigned short* WoT   = us + 7340032;        // 1024x1024
    unsigned short* Qb    = us + 8388608;        // 4096x1024 (roped, *scale*log2e)
    unsigned short* Kb    = us + 12582912;       // 4096x1024 (roped)
    unsigned short* Vt    = us + 16777216;       // [b][h][d][s] = [2][16][64][2048]
    unsigned short* AO    = us + 20971520;
    float* cosT = (float*)((char*)d_ws + 50331648);
    float* sinT = cosT + 65536;

    k_convert<<<2048, 256, 0, stream>>>(x, xb);
    k_transw<<<dim3(32, 32, 4), dim3(32, 8), 0, stream>>>(
        Wq, Wk, Wv, Wo, WqkvT, WqkvT + 1048576, WqkvT + 2097152, WoT);
    k_rope_table<<<256, 256, 0, stream>>>(cosT, sinT);
    k_gemmN<128, 64, 48, true><<<dim3(48, 32), 256, 0, stream>>>(
        xb, WqkvT, Qb, Kb, Vt, nullptr, cosT, sinT);
    k_attn<<<dim3(32, 32), 128, 0, stream>>>(Qb, Kb, Vt, AO);
    k_gemmN<128, 64, 16, false><<<dim3(16, 32), 256, 0, stream>>>(
        AO, WoT, nullptr, nullptr, nullptr, (float*)d_out, cosT, sinT);
}

// Round 10
// 125.598 us; speedup vs baseline: 1.2034x; 1.2034x over previous
//
#include <hip/hip_runtime.h>
#include <hip/hip_bf16.h>

#define S_LEN 2048
#define E_DIM 1024
#define NH 16
#define HD 64
#define ATTN_SCALE 0.03125f                 // 1/sqrt(1024)
#define QSCALE_L2E 0.045084312f             // ATTN_SCALE * log2(e): exp2-domain softmax
#define KVB 128

typedef __attribute__((ext_vector_type(8))) short short8;
typedef __attribute__((ext_vector_type(8))) unsigned short ushort8;
typedef __attribute__((ext_vector_type(4))) unsigned short ushort4_t;
typedef __attribute__((ext_vector_type(4))) float f32x4;
typedef __attribute__((ext_vector_type(4))) float f4;
typedef __attribute__((ext_vector_type(2))) unsigned int uint2_t;

__device__ __forceinline__ float bf2f(unsigned short u) {
    unsigned int x = ((unsigned int)u) << 16;
    return __builtin_bit_cast(float, x);
}
__device__ __forceinline__ unsigned short f2bf(float f) {
    unsigned int x = __builtin_bit_cast(unsigned int, f);
    x += 0x7FFFu + ((x >> 16) & 1u);   // RNE
    return (unsigned short)(x >> 16);
}
__device__ __forceinline__ void gload16(const unsigned short* g, unsigned short* l) {
    __builtin_amdgcn_global_load_lds(
        (__attribute__((address_space(1))) void*)g,
        (__attribute__((address_space(3))) void*)l, 16, 0, 0);
}

// ---------------- x f32 -> bf16 ----------------
__global__ __launch_bounds__(256) void k_convert(const float* __restrict__ x,
                                                 unsigned short* __restrict__ xb) {
    size_t i = ((size_t)blockIdx.x * 256 + threadIdx.x) * 8;
    f4 a = *(const f4*)(x + i);
    f4 b = *(const f4*)(x + i + 4);
    ushort8 o;
    o[0] = f2bf(a[0]); o[1] = f2bf(a[1]); o[2] = f2bf(a[2]); o[3] = f2bf(a[3]);
    o[4] = f2bf(b[0]); o[5] = f2bf(b[1]); o[6] = f2bf(b[2]); o[7] = f2bf(b[3]);
    *(ushort8*)(xb + i) = o;
}

// ---------------- W f32 -> bf16 transposed (Wt[n][k] = W[k][n]) ----------------
__global__ __launch_bounds__(256) void k_transw(const float* W0, const float* W1,
                                                const float* W2, const float* W3,
                                                unsigned short* T0, unsigned short* T1,
                                                unsigned short* T2, unsigned short* T3) {
    const float* W; unsigned short* T;
    switch (blockIdx.z) {
        case 0: W = W0; T = T0; break;
        case 1: W = W1; T = T1; break;
        case 2: W = W2; T = T2; break;
        default: W = W3; T = T3; break;
    }
    __shared__ float tile[32][33];
    int tx = threadIdx.x, ty = threadIdx.y;
    int bx = blockIdx.x * 32, by = blockIdx.y * 32;
#pragma unroll
    for (int i = 0; i < 4; i++)
        tile[ty + i * 8][tx] = W[(size_t)(by + ty + i * 8) * E_DIM + bx + tx];
    __syncthreads();
#pragma unroll
    for (int i = 0; i < 4; i++)
        T[(size_t)(bx + ty + i * 8) * E_DIM + by + tx] = f2bf(tile[tx][ty + i * 8]);
}

// ---------------- RoPE cos/sin table: [2048][32] ----------------
__global__ __launch_bounds__(256) void k_rope_table(float* __restrict__ cosT,
                                                    float* __restrict__ sinT) {
    int idx = blockIdx.x * 256 + threadIdx.x;
    int s = idx >> 5, j = idx & 31;
    float inv = expf(-(float)j * (9.210340371976184f / 32.f));
    float ang = (float)s * inv;
    cosT[idx] = cosf(ang);
    sinT[idx] = sinf(ang);
}

// ---------------- bf16 GEMM: small-tile 2-phase counted-vmcnt, 3 wgs/CU ----------
// QKV3: B = [Wq;Wk;Wv] -> RoPE'd Q (scaled by ATTN_SCALE*log2e), RoPE'd K, V^T.
template <int BM, int BN, int NBN, bool QKV3>
__global__ __launch_bounds__(256, 3)
void k_gemmN(const unsigned short* __restrict__ A,
             const unsigned short* __restrict__ B,
             unsigned short* __restrict__ Qo,
             unsigned short* __restrict__ Ko,
             unsigned short* __restrict__ Vto,
             float* __restrict__ Fo,
             const float* __restrict__ cosT,
             const float* __restrict__ sinT) {
    constexpr int THREADS = 256;
    constexpr int WM = BM / 2, WN = BN / 2;
    constexpr int FM = WM / 16, FN = WN / 16;
    constexpr int NT = E_DIM / 64;
    constexpr int AR = BM * 8 / THREADS;
    constexpr int BR = BN * 8 / THREADS;
    constexpr int STG = AR + BR;
    constexpr int NWG = (4096 / BM) * NBN;
    __shared__ unsigned short Al[2][BM * 64];
    __shared__ unsigned short Bl[2][BN * 64];
    int tid = threadIdx.x, lane = tid & 63, wid = tid >> 6;
    int l15 = lane & 15, lg = lane >> 4;
    int wr = wid >> 1, wc = wid & 1;
    int orig = blockIdx.y * NBN + blockIdx.x;
    int wg = (orig & 7) * (NWG / 8) + (orig >> 3);   // bijective XCD swizzle
    int bm = wg / NBN, bn = wg % NBN;

    auto stage = [&](int buf, int k0) {
#pragma unroll
        for (int i = 0; i < AR; i++) {
            int r = i * (THREADS / 8) + wid * 8 + (lane >> 3);
            int cs = (lane & 7) ^ (r & 7);
            gload16(A + (size_t)(bm * BM + r) * E_DIM + k0 + cs * 8,
                    &Al[buf][i * (THREADS * 8) + wid * 512]);
        }
#pragma unroll
        for (int i = 0; i < BR; i++) {
            int r = i * (THREADS / 8) + wid * 8 + (lane >> 3);
            int cs = (lane & 7) ^ (r & 7);
            gload16(B + (size_t)(bn * BN + r) * E_DIM + k0 + cs * 8,
                    &Bl[buf][i * (THREADS * 8) + wid * 512]);
        }
    };

    f32x4 acc[FM][FN] = {};
    stage(0, 0);
    for (int t = 0; t < NT; t++) {
        int cur = t & 1;
        if (t + 1 < NT) {
            stage(cur ^ 1, (t + 1) * 64);
            asm volatile("s_waitcnt vmcnt(%0)" :: "n"(STG) : "memory");
        } else {
            asm volatile("s_waitcnt vmcnt(0)" ::: "memory");
        }
        __builtin_amdgcn_s_barrier();
        __builtin_amdgcn_sched_barrier(0);
#pragma unroll
        for (int ks = 0; ks < 2; ks++) {
            short8 af[FM], bfv[FN];
#pragma unroll
            for (int m = 0; m < FM; m++) {
                int r = wr * WM + m * 16 + l15;
                int gc = ks * 4 + lg;
                af[m] = *(const short8*)&Al[cur][r * 64 + ((gc ^ (r & 7)) << 3)];
            }
#pragma unroll
            for (int n = 0; n < FN; n++) {
                int r = wc * WN + n * 16 + l15;
                int gc = ks * 4 + lg;
                bfv[n] = *(const short8*)&Bl[cur][r * 64 + ((gc ^ (r & 7)) << 3)];
            }
            __builtin_amdgcn_s_setprio(1);
#pragma unroll
            for (int m = 0; m < FM; m++)
#pragma unroll
                for (int n = 0; n < FN; n++)
                    acc[m][n] = __builtin_amdgcn_mfma_f32_16x16x32_bf16(
                        af[m], bfv[n], acc[m][n], 0, 0, 0);
            __builtin_amdgcn_s_setprio(0);
        }
        __builtin_amdgcn_s_barrier();
    }
    // epilogue
#pragma unroll
    for (int m = 0; m < FM; m++) {
        int r0 = bm * BM + wr * WM + m * 16 + lg * 4;
#pragma unroll
        for (int n = 0; n < FN; n++) {
            int colg = bn * BN + wc * WN + n * 16 + l15;
            if (QKV3) {
                int z = colg >> 10, c1 = colg & 1023;
                if (z == 2) {
                    int h = c1 >> 6, d = c1 & 63;
                    int bb = r0 >> 11, s = r0 & 2047;
                    ushort4_t p;
#pragma unroll
                    for (int r = 0; r < 4; r++) p[r] = f2bf(acc[m][n][r]);
                    *(ushort4_t*)(Vto + (((size_t)((bb * 16 + h) * 64 + d)) << 11) + s) = p;
                } else {
                    // fused interleaved RoPE; Q scaled by ATTN_SCALE*log2e
                    unsigned short* T = z ? Ko : Qo;
                    int dl = c1 & 63, j = dl >> 1;
                    float sgn = (dl & 1) ? 1.f : -1.f;
                    float scq = z ? 1.f : QSCALE_L2E;
#pragma unroll
                    for (int r = 0; r < 4; r++) {
                        int row = r0 + r, s = row & 2047;
                        float c = cosT[s * 32 + j], sn = sinT[s * 32 + j];
                        float v = acc[m][n][r];
                        float p = __shfl_xor(v, 1);
                        T[(size_t)row * E_DIM + c1] = f2bf((v * c + sgn * p * sn) * scq);
                    }
                }
            } else {
#pragma unroll
                for (int r = 0; r < 4; r++)
                    Fo[(size_t)(r0 + r) * E_DIM + colg] = acc[m][n][r];
            }
        }
    }
}

// ---------------- causal flash attention v4 (R7 structure + occupancy + VALU cuts)
// 4 waves x 16 q-rows = 64 q-rows/block; 1024 blocks (one q-tile each, big tiles
// dispatched first), 3 blocks/CU (50KB LDS). KV tiles of 128, R7's 4-barrier
// counted-vmcnt schedule. exp2-domain softmax, defer-max (THR=8), cvt_pk P->bf16.
__global__ __launch_bounds__(256, 3) void k_attn(const unsigned short* __restrict__ Q,
                                                 const unsigned short* __restrict__ K,
                                                 const unsigned short* __restrict__ Vt,
                                                 unsigned short* __restrict__ O) {
    __shared__ unsigned short K_lds[128 * 64];
    __shared__ unsigned short V_lds[64 * 128];
    __shared__ unsigned short P_lds[4][16][136];
    int tid = threadIdx.x, lane = tid & 63, wid = tid >> 6;
    int l15 = lane & 15, lg = lane >> 4;
    int orig = blockIdx.y * 32 + blockIdx.x;         // 1024 wgs
    int wg = (orig & 7) * 128 + (orig >> 3);         // XCD swizzle: 4 bh per XCD
    int qt = 31 - (wg & 31);                         // big tiles first in dispatch
    int bh = wg >> 5;
    int b = bh >> 4, h = bh & 15;
    const size_t base_qk = (size_t)b * S_LEN * E_DIM + (size_t)h * HD;
    const unsigned short* Vbh = Vt + ((size_t)(bh * 64) << 11);

    auto stageK = [&](int kt) {
        const unsigned short* Kb = K + base_qk + (size_t)(kt * KVB) * E_DIM;
#pragma unroll
        for (int i = 0; i < 4; i++) {
            int r = i * 32 + wid * 8 + (lane >> 3);
            int cs = (lane & 7) ^ (r & 7);
            gload16(Kb + (size_t)r * E_DIM + cs * 8, K_lds + i * 2048 + wid * 512);
        }
    };
    auto stageV = [&](int kt) {
#pragma unroll
        for (int i = 0; i < 4; i++) {
            int r = i * 16 + wid * 4 + (lane >> 4);
            int cs = (lane & 15) ^ (r & 7);
            gload16(Vbh + (size_t)r * 2048 + kt * KVB + cs * 8,
                    V_lds + i * 2048 + wid * 512);
        }
    };

    const unsigned short* Qb = Q + base_qk + (size_t)(qt * 64 + wid * 16) * E_DIM;
    short8 bq[2];
#pragma unroll
    for (int s2 = 0; s2 < 2; s2++)
        bq[s2] = *(const short8*)(Qb + (size_t)l15 * E_DIM + s2 * 32 + lg * 8);
    f32x4 acc_o[4] = {};
    float m_i = -1e30f, l_i = 0.f;
    int q_glob = qt * 64 + wid * 16 + l15;
    int nkt = (qt + 2) >> 1;
    stageK(0);
    stageV(0);
    asm volatile("s_waitcnt vmcnt(4)" ::: "memory");   // own K0 done
    __builtin_amdgcn_s_barrier();                      // all waves' K0 landed
    __builtin_amdgcn_sched_barrier(0);
    for (int kt = 0; kt < nkt; ++kt) {
        // S^T = K . Q^T (exp2 domain; scale*log2e pre-folded into Q)
        f32x4 acc_s[8] = {};
        __builtin_amdgcn_s_setprio(1);
#pragma unroll
        for (int mf = 0; mf < 8; mf++) {
            int rK = mf * 16 + l15;
#pragma unroll
            for (int s2 = 0; s2 < 2; s2++) {
                int gc = s2 * 4 + lg;
                short8 a = *(const short8*)&K_lds[rK * 64 + ((gc ^ (rK & 7)) << 3)];
                acc_s[mf] = __builtin_amdgcn_mfma_f32_16x16x32_bf16(
                    a, bq[s2], acc_s[mf], 0, 0, 0);
            }
        }
        __builtin_amdgcn_s_setprio(0);
        __builtin_amdgcn_s_barrier();       // B1: K_lds free
        if (kt + 1 < nkt) stageK(kt + 1);
        float sv[32];
        float vmax = -1e30f;
        if (kt == nkt - 1) {
#pragma unroll
            for (int mf = 0; mf < 8; mf++)
#pragma unroll
                for (int r = 0; r < 4; r++) {
                    int kg = kt * KVB + mf * 16 + lg * 4 + r;
                    float v = acc_s[mf][r];
                    if (kg > q_glob) v = -1e30f;
                    sv[mf * 4 + r] = v;
                    vmax = fmaxf(vmax, v);
                }
        } else {
#pragma unroll
            for (int mf = 0; mf < 8; mf++)
#pragma unroll
                for (int r = 0; r < 4; r++) {
                    float v = acc_s[mf][r];
                    sv[mf * 4 + r] = v;
                    vmax = fmaxf(vmax, v);
                }
        }
        vmax = fmaxf(vmax, __shfl_xor(vmax, 16));
        vmax = fmaxf(vmax, __shfl_xor(vmax, 32));
        // defer-max (T13): rescale only when tile max grew by > 8 (exp2 domain)
        if (!__all(vmax - m_i <= 8.0f)) {
            float m_new = fmaxf(m_i, vmax);
            float corr = exp2f(m_i - m_new);
            l_i *= corr;
#pragma unroll
            for (int r = 0; r < 4; r++) {
                float c4 = __shfl(corr, lg * 4 + r);
#pragma unroll
                for (int nf = 0; nf < 4; nf++) acc_o[nf][r] *= c4;
            }
            m_i = m_new;
        }
        float rowsum = 0.f;
#pragma unroll
        for (int i = 0; i < 32; i++) {
            float p = exp2f(sv[i] - m_i);
            sv[i] = p;
            rowsum += p;
        }
        rowsum += __shfl_xor(rowsum, 16);
        rowsum += __shfl_xor(rowsum, 32);
        l_i += rowsum;
        // P -> bf16 via cvt_pk, wave-private LDS [q][k]
#pragma unroll
        for (int mf = 0; mf < 8; mf++) {
            unsigned int w0, w1;
            asm("v_cvt_pk_bf16_f32 %0, %1, %2"
                : "=v"(w0) : "v"(sv[mf * 4 + 0]), "v"(sv[mf * 4 + 1]));
            asm("v_cvt_pk_bf16_f32 %0, %1, %2"
                : "=v"(w1) : "v"(sv[mf * 4 + 2]), "v"(sv[mf * 4 + 3]));
            uint2_t w; w[0] = w0; w[1] = w1;
            *(uint2_t*)&P_lds[wid][l15][mf * 16 + lg * 4] = w;
        }
        if (kt + 1 < nkt)
            asm volatile("s_waitcnt vmcnt(4)" ::: "memory");  // own V(kt) done
        else
            asm volatile("s_waitcnt vmcnt(0)" ::: "memory");
        __builtin_amdgcn_s_barrier();       // B2: all V(kt) landed
        __builtin_amdgcn_sched_barrier(0);
        // PV: O += P . V
        __builtin_amdgcn_s_setprio(1);
#pragma unroll
        for (int s2 = 0; s2 < 4; s2++) {
            short8 pa = *(const short8*)&P_lds[wid][l15][s2 * 32 + lg * 8];
#pragma unroll
            for (int nf = 0; nf < 4; nf++) {
                int rV = nf * 16 + l15;
                int gc = s2 * 4 + lg;
                short8 bv = *(const short8*)&V_lds[rV * 128 + ((gc ^ (rV & 7)) << 3)];
                acc_o[nf] = __builtin_amdgcn_mfma_f32_16x16x32_bf16(
                    pa, bv, acc_o[nf], 0, 0, 0);
            }
        }
        __builtin_amdgcn_s_setprio(0);
        __builtin_amdgcn_s_barrier();       // B3: V_lds free
        if (kt + 1 < nkt) {
            stageV(kt + 1);
            asm volatile("s_waitcnt vmcnt(4)" ::: "memory");  // own K(kt+1) done
        }
        __builtin_amdgcn_s_barrier();       // B4: all K(kt+1) landed
        __builtin_amdgcn_sched_barrier(0);
    }
    unsigned short* Ob = O + base_qk + (size_t)(qt * 64 + wid * 16) * E_DIM;
#pragma unroll
    for (int r = 0; r < 4; r++) {
        float linv = 1.f / __shfl(l_i, lg * 4 + r);
#pragma unroll
        for (int nf = 0; nf < 4; nf++)
            Ob[(size_t)(lg * 4 + r) * E_DIM + nf * 16 + l15] =
                f2bf(acc_o[nf][r] * linv);
    }
}

extern "C" void kernel_launch(void* const* d_in, const int* in_sizes, int n_in,
                              void* d_out, int out_size, void* d_ws, size_t ws_size,
                              hipStream_t stream) {
    (void)in_sizes; (void)n_in; (void)out_size; (void)ws_size;
    const float* x  = (const float*)d_in[0];
    const float* Wq = (const float*)d_in[1];
    const float* Wk = (const float*)d_in[2];
    const float* Wv = (const float*)d_in[3];
    const float* Wo = (const float*)d_in[4];

    unsigned short* us = (unsigned short*)d_ws;
    unsigned short* xb    = us;                  // 4096x1024
    unsigned short* WqkvT = us + 4194304;        // 3072x1024 (Wq;Wk;Wv rows)
    unsigned short* WoT   = us + 7340032;        // 1024x1024
    unsigned short* Qb    = us + 8388608;        // 4096x1024 (roped, *scale*log2e)
    unsigned short* Kb    = us + 12582912;       // 4096x1024 (roped)
    unsigned short* Vt    = us + 16777216;       // [b][h][d][s] = [2][16][64][2048]
    unsigned short* AO    = us + 20971520;
    float* cosT = (float*)((char*)d_ws + 50331648);
    float* sinT = cosT + 65536;

    k_convert<<<2048, 256, 0, stream>>>(x, xb);
    k_transw<<<dim3(32, 32, 4), dim3(32, 8), 0, stream>>>(
        Wq, Wk, Wv, Wo, WqkvT, WqkvT + 1048576, WqkvT + 2097152, WoT);
    k_rope_table<<<256, 256, 0, stream>>>(cosT, sinT);
    k_gemmN<128, 64, 48, true><<<dim3(48, 32), 256, 0, stream>>>(
        xb, WqkvT, Qb, Kb, Vt, nullptr, cosT, sinT);
    k_attn<<<dim3(32, 32), 256, 0, stream>>>(Qb, Kb, Vt, AO);
    k_gemmN<128, 64, 16, false><<<dim3(16, 32), 256, 0, stream>>>(
        AO, WoT, nullptr, nullptr, nullptr, (float*)d_out, cosT, sinT);
}

// Round 11
// 107.419 us; speedup vs baseline: 1.4070x; 1.1692x over previous
//
#include <hip/hip_runtime.h>
#include <hip/hip_bf16.h>

#define S_LEN 2048
#define E_DIM 1024
#define NH 16
#define HD 64
#define ATTN_SCALE 0.03125f                 // 1/sqrt(1024)
#define QSCALE_L2E 0.045084312f             // ATTN_SCALE * log2(e): exp2-domain softmax
#define KVB 128

typedef __attribute__((ext_vector_type(8))) short short8;
typedef __attribute__((ext_vector_type(8))) unsigned short ushort8;
typedef __attribute__((ext_vector_type(4))) unsigned short ushort4_t;
typedef __attribute__((ext_vector_type(4))) float f32x4;
typedef __attribute__((ext_vector_type(4))) float f4;
typedef __attribute__((ext_vector_type(2))) unsigned int uint2_t;

__device__ __forceinline__ float bf2f(unsigned short u) {
    unsigned int x = ((unsigned int)u) << 16;
    return __builtin_bit_cast(float, x);
}
__device__ __forceinline__ unsigned short f2bf(float f) {
    unsigned int x = __builtin_bit_cast(unsigned int, f);
    x += 0x7FFFu + ((x >> 16) & 1u);   // RNE
    return (unsigned short)(x >> 16);
}
__device__ __forceinline__ float exp2_fast(float x) {   // 2^x, one v_exp_f32
    float r;
    asm("v_exp_f32 %0, %1" : "=v"(r) : "v"(x));
    return r;
}
__device__ __forceinline__ void gload16(const unsigned short* g, unsigned short* l) {
    __builtin_amdgcn_global_load_lds(
        (__attribute__((address_space(1))) void*)g,
        (__attribute__((address_space(3))) void*)l, 16, 0, 0);
}

// ---------------- x f32 -> bf16 ----------------
__global__ __launch_bounds__(256) void k_convert(const float* __restrict__ x,
                                                 unsigned short* __restrict__ xb) {
    size_t i = ((size_t)blockIdx.x * 256 + threadIdx.x) * 8;
    f4 a = *(const f4*)(x + i);
    f4 b = *(const f4*)(x + i + 4);
    ushort8 o;
    o[0] = f2bf(a[0]); o[1] = f2bf(a[1]); o[2] = f2bf(a[2]); o[3] = f2bf(a[3]);
    o[4] = f2bf(b[0]); o[5] = f2bf(b[1]); o[6] = f2bf(b[2]); o[7] = f2bf(b[3]);
    *(ushort8*)(xb + i) = o;
}

// ---------------- W f32 -> bf16 transposed (Wt[n][k] = W[k][n]) ----------------
__global__ __launch_bounds__(256) void k_transw(const float* W0, const float* W1,
                                                const float* W2, const float* W3,
                                                unsigned short* T0, unsigned short* T1,
                                                unsigned short* T2, unsigned short* T3) {
    const float* W; unsigned short* T;
    switch (blockIdx.z) {
        case 0: W = W0; T = T0; break;
        case 1: W = W1; T = T1; break;
        case 2: W = W2; T = T2; break;
        default: W = W3; T = T3; break;
    }
    __shared__ float tile[32][33];
    int tx = threadIdx.x, ty = threadIdx.y;
    int bx = blockIdx.x * 32, by = blockIdx.y * 32;
#pragma unroll
    for (int i = 0; i < 4; i++)
        tile[ty + i * 8][tx] = W[(size_t)(by + ty + i * 8) * E_DIM + bx + tx];
    __syncthreads();
#pragma unroll
    for (int i = 0; i < 4; i++)
        T[(size_t)(bx + ty + i * 8) * E_DIM + by + tx] = f2bf(tile[tx][ty + i * 8]);
}

// ---------------- RoPE cos/sin table: [2048][32] ----------------
__global__ __launch_bounds__(256) void k_rope_table(float* __restrict__ cosT,
                                                    float* __restrict__ sinT) {
    int idx = blockIdx.x * 256 + threadIdx.x;
    int s = idx >> 5, j = idx & 31;
    float inv = expf(-(float)j * (9.210340371976184f / 32.f));
    float ang = (float)s * inv;
    cosT[idx] = cosf(ang);
    sinT[idx] = sinf(ang);
}

// ---------------- bf16 GEMM: small-tile 2-phase counted-vmcnt, 3 wgs/CU ----------
// QKV3: B = [Wq;Wk;Wv] -> RoPE'd Q (scaled by ATTN_SCALE*log2e), RoPE'd K, V^T.
template <int BM, int BN, int NBN, bool QKV3>
__global__ __launch_bounds__(256, 3)
void k_gemmN(const unsigned short* __restrict__ A,
             const unsigned short* __restrict__ B,
             unsigned short* __restrict__ Qo,
             unsigned short* __restrict__ Ko,
             unsigned short* __restrict__ Vto,
             float* __restrict__ Fo,
             const float* __restrict__ cosT,
             const float* __restrict__ sinT) {
    constexpr int THREADS = 256;
    constexpr int WM = BM / 2, WN = BN / 2;
    constexpr int FM = WM / 16, FN = WN / 16;
    constexpr int NT = E_DIM / 64;
    constexpr int AR = BM * 8 / THREADS;
    constexpr int BR = BN * 8 / THREADS;
    constexpr int STG = AR + BR;
    constexpr int NWG = (4096 / BM) * NBN;
    __shared__ unsigned short Al[2][BM * 64];
    __shared__ unsigned short Bl[2][BN * 64];
    int tid = threadIdx.x, lane = tid & 63, wid = tid >> 6;
    int l15 = lane & 15, lg = lane >> 4;
    int wr = wid >> 1, wc = wid & 1;
    int orig = blockIdx.y * NBN + blockIdx.x;
    int wg = (orig & 7) * (NWG / 8) + (orig >> 3);   // bijective XCD swizzle
    int bm = wg / NBN, bn = wg % NBN;

    auto stage = [&](int buf, int k0) {
#pragma unroll
        for (int i = 0; i < AR; i++) {
            int r = i * (THREADS / 8) + wid * 8 + (lane >> 3);
            int cs = (lane & 7) ^ (r & 7);
            gload16(A + (size_t)(bm * BM + r) * E_DIM + k0 + cs * 8,
                    &Al[buf][i * (THREADS * 8) + wid * 512]);
        }
#pragma unroll
        for (int i = 0; i < BR; i++) {
            int r = i * (THREADS / 8) + wid * 8 + (lane >> 3);
            int cs = (lane & 7) ^ (r & 7);
            gload16(B + (size_t)(bn * BN + r) * E_DIM + k0 + cs * 8,
                    &Bl[buf][i * (THREADS * 8) + wid * 512]);
        }
    };

    f32x4 acc[FM][FN] = {};
    stage(0, 0);
    for (int t = 0; t < NT; t++) {
        int cur = t & 1;
        if (t + 1 < NT) {
            stage(cur ^ 1, (t + 1) * 64);
            asm volatile("s_waitcnt vmcnt(%0)" :: "n"(STG) : "memory");
        } else {
            asm volatile("s_waitcnt vmcnt(0)" ::: "memory");
        }
        __builtin_amdgcn_s_barrier();
        __builtin_amdgcn_sched_barrier(0);
#pragma unroll
        for (int ks = 0; ks < 2; ks++) {
            short8 af[FM], bfv[FN];
#pragma unroll
            for (int m = 0; m < FM; m++) {
                int r = wr * WM + m * 16 + l15;
                int gc = ks * 4 + lg;
                af[m] = *(const short8*)&Al[cur][r * 64 + ((gc ^ (r & 7)) << 3)];
            }
#pragma unroll
            for (int n = 0; n < FN; n++) {
                int r = wc * WN + n * 16 + l15;
                int gc = ks * 4 + lg;
                bfv[n] = *(const short8*)&Bl[cur][r * 64 + ((gc ^ (r & 7)) << 3)];
            }
            __builtin_amdgcn_s_setprio(1);
#pragma unroll
            for (int m = 0; m < FM; m++)
#pragma unroll
                for (int n = 0; n < FN; n++)
                    acc[m][n] = __builtin_amdgcn_mfma_f32_16x16x32_bf16(
                        af[m], bfv[n], acc[m][n], 0, 0, 0);
            __builtin_amdgcn_s_setprio(0);
        }
        __builtin_amdgcn_s_barrier();
    }
    // epilogue
#pragma unroll
    for (int m = 0; m < FM; m++) {
        int r0 = bm * BM + wr * WM + m * 16 + lg * 4;
#pragma unroll
        for (int n = 0; n < FN; n++) {
            int colg = bn * BN + wc * WN + n * 16 + l15;
            if (QKV3) {
                int z = colg >> 10, c1 = colg & 1023;
                if (z == 2) {
                    int h = c1 >> 6, d = c1 & 63;
                    int bb = r0 >> 11, s = r0 & 2047;
                    ushort4_t p;
#pragma unroll
                    for (int r = 0; r < 4; r++) p[r] = f2bf(acc[m][n][r]);
                    *(ushort4_t*)(Vto + (((size_t)((bb * 16 + h) * 64 + d)) << 11) + s) = p;
                } else {
                    // fused interleaved RoPE; Q scaled by ATTN_SCALE*log2e
                    unsigned short* T = z ? Ko : Qo;
                    int dl = c1 & 63, j = dl >> 1;
                    float sgn = (dl & 1) ? 1.f : -1.f;
                    float scq = z ? 1.f : QSCALE_L2E;
#pragma unroll
                    for (int r = 0; r < 4; r++) {
                        int row = r0 + r, s = row & 2047;
                        float c = cosT[s * 32 + j], sn = sinT[s * 32 + j];
                        float v = acc[m][n][r];
                        float p = __shfl_xor(v, 1);
                        T[(size_t)row * E_DIM + c1] = f2bf((v * c + sgn * p * sn) * scq);
                    }
                }
            } else {
#pragma unroll
                for (int r = 0; r < 4; r++)
                    Fo[(size_t)(r0 + r) * E_DIM + colg] = acc[m][n][r];
            }
        }
    }
}

// ---------------- causal flash attention (R7 structure + raw v_exp + cvt_pk) ----
// 4 waves x 16 q-rows; q-tile pair (jp, 31-jp) -> 17 KV tiles of 128 per block.
// 4 light raw barriers per tile, counted vmcnt; exp2-domain softmax (log2e
// pre-folded into Q), exponentials = single v_exp_f32, P->bf16 via cvt_pk.
__global__ __launch_bounds__(256, 2) void k_attn(const unsigned short* __restrict__ Q,
                                                 const unsigned short* __restrict__ K,
                                                 const unsigned short* __restrict__ Vt,
                                                 unsigned short* __restrict__ O) {
    __shared__ unsigned short K_lds[128 * 64];
    __shared__ unsigned short V_lds[64 * 128];
    __shared__ unsigned short P_lds[4][16][136];
    int tid = threadIdx.x, lane = tid & 63, wid = tid >> 6;
    int l15 = lane & 15, lg = lane >> 4;
    int orig = blockIdx.y * 16 + blockIdx.x;         // 512 wgs
    int wg = (orig & 7) * 64 + (orig >> 3);          // XCD swizzle
    int jp = wg & 15, bh = wg >> 4;
    int b = bh >> 4, h = bh & 15;
    const size_t base_qk = (size_t)b * S_LEN * E_DIM + (size_t)h * HD;
    const unsigned short* Vbh = Vt + ((size_t)(bh * 64) << 11);

    auto stageK = [&](int kt) {
        const unsigned short* Kb = K + base_qk + (size_t)(kt * KVB) * E_DIM;
#pragma unroll
        for (int i = 0; i < 4; i++) {
            int r = i * 32 + wid * 8 + (lane >> 3);
            int cs = (lane & 7) ^ (r & 7);
            gload16(Kb + (size_t)r * E_DIM + cs * 8, K_lds + i * 2048 + wid * 512);
        }
    };
    auto stageV = [&](int kt) {
#pragma unroll
        for (int i = 0; i < 4; i++) {
            int r = i * 16 + wid * 4 + (lane >> 4);
            int cs = (lane & 15) ^ (r & 7);
            gload16(Vbh + (size_t)r * 2048 + kt * KVB + cs * 8,
                    V_lds + i * 2048 + wid * 512);
        }
    };

    for (int pass = 0; pass < 2; ++pass) {
        int qt = pass ? (31 - jp) : jp;
        const unsigned short* Qb = Q + base_qk + (size_t)(qt * 64 + wid * 16) * E_DIM;
        short8 bq[2];
#pragma unroll
        for (int s2 = 0; s2 < 2; s2++)
            bq[s2] = *(const short8*)(Qb + (size_t)l15 * E_DIM + s2 * 32 + lg * 8);
        f32x4 acc_o[4] = {};
        float m_i = -1e30f, l_i = 0.f;
        int q_glob = qt * 64 + wid * 16 + l15;
        int nkt = (qt + 2) >> 1;
        stageK(0);
        stageV(0);
        asm volatile("s_waitcnt vmcnt(4)" ::: "memory");   // own K0 done
        __builtin_amdgcn_s_barrier();                      // all waves' K0 landed
        __builtin_amdgcn_sched_barrier(0);
        for (int kt = 0; kt < nkt; ++kt) {
            // S^T = K . Q^T (exp2 domain; scale*log2e pre-folded into Q)
            f32x4 acc_s[8] = {};
            __builtin_amdgcn_s_setprio(1);
#pragma unroll
            for (int mf = 0; mf < 8; mf++) {
                int rK = mf * 16 + l15;
#pragma unroll
                for (int s2 = 0; s2 < 2; s2++) {
                    int gc = s2 * 4 + lg;
                    short8 a = *(const short8*)&K_lds[rK * 64 + ((gc ^ (rK & 7)) << 3)];
                    acc_s[mf] = __builtin_amdgcn_mfma_f32_16x16x32_bf16(
                        a, bq[s2], acc_s[mf], 0, 0, 0);
                }
            }
            __builtin_amdgcn_s_setprio(0);
            __builtin_amdgcn_s_barrier();       // B1: K_lds free
            if (kt + 1 < nkt) stageK(kt + 1);
            float sv[32];
            float vmax = -1e30f;
            if (kt == nkt - 1) {
#pragma unroll
                for (int mf = 0; mf < 8; mf++)
#pragma unroll
                    for (int r = 0; r < 4; r++) {
                        int kg = kt * KVB + mf * 16 + lg * 4 + r;
                        float v = acc_s[mf][r];
                        if (kg > q_glob) v = -1e30f;
                        sv[mf * 4 + r] = v;
                        vmax = fmaxf(vmax, v);
                    }
            } else {
#pragma unroll
                for (int mf = 0; mf < 8; mf++)
#pragma unroll
                    for (int r = 0; r < 4; r++) {
                        float v = acc_s[mf][r];
                        sv[mf * 4 + r] = v;
                        vmax = fmaxf(vmax, v);
                    }
            }
            vmax = fmaxf(vmax, __shfl_xor(vmax, 16));
            vmax = fmaxf(vmax, __shfl_xor(vmax, 32));
            float m_new = fmaxf(m_i, vmax);
            float corr = exp2_fast(m_i - m_new);
            float rowsum = 0.f;
#pragma unroll
            for (int i = 0; i < 32; i++) {
                float p = exp2_fast(sv[i] - m_new);
                sv[i] = p;
                rowsum += p;
            }
            rowsum += __shfl_xor(rowsum, 16);
            rowsum += __shfl_xor(rowsum, 32);
            l_i = l_i * corr + rowsum;
            m_i = m_new;
            // P -> bf16 via cvt_pk, wave-private LDS [q][k]
#pragma unroll
            for (int mf = 0; mf < 8; mf++) {
                unsigned int w0, w1;
                asm("v_cvt_pk_bf16_f32 %0, %1, %2"
                    : "=v"(w0) : "v"(sv[mf * 4 + 0]), "v"(sv[mf * 4 + 1]));
                asm("v_cvt_pk_bf16_f32 %0, %1, %2"
                    : "=v"(w1) : "v"(sv[mf * 4 + 2]), "v"(sv[mf * 4 + 3]));
                uint2_t w; w[0] = w0; w[1] = w1;
                *(uint2_t*)&P_lds[wid][l15][mf * 16 + lg * 4] = w;
            }
            // rescale O accumulator (rows at lg*4+r; corr lives at lane q)
#pragma unroll
            for (int r = 0; r < 4; r++) {
                float c4 = __shfl(corr, lg * 4 + r);
#pragma unroll
                for (int nf = 0; nf < 4; nf++) acc_o[nf][r] *= c4;
            }
            if (kt + 1 < nkt)
                asm volatile("s_waitcnt vmcnt(4)" ::: "memory");  // own V(kt) done
            else
                asm volatile("s_waitcnt vmcnt(0)" ::: "memory");
            __builtin_amdgcn_s_barrier();       // B2: all V(kt) landed
            __builtin_amdgcn_sched_barrier(0);
            // PV: O += P . V
            __builtin_amdgcn_s_setprio(1);
#pragma unroll
            for (int s2 = 0; s2 < 4; s2++) {
                short8 pa = *(const short8*)&P_lds[wid][l15][s2 * 32 + lg * 8];
#pragma unroll
                for (int nf = 0; nf < 4; nf++) {
                    int rV = nf * 16 + l15;
                    int gc = s2 * 4 + lg;
                    short8 bv = *(const short8*)&V_lds[rV * 128 + ((gc ^ (rV & 7)) << 3)];
                    acc_o[nf] = __builtin_amdgcn_mfma_f32_16x16x32_bf16(
                        pa, bv, acc_o[nf], 0, 0, 0);
                }
            }
            __builtin_amdgcn_s_setprio(0);
            __builtin_amdgcn_s_barrier();       // B3: V_lds free
            if (kt + 1 < nkt) {
                stageV(kt + 1);
                asm volatile("s_waitcnt vmcnt(4)" ::: "memory");  // own K(kt+1) done
            }
            __builtin_amdgcn_s_barrier();       // B4: all K(kt+1) landed
            __builtin_amdgcn_sched_barrier(0);
        }
        unsigned short* Ob = O + base_qk + (size_t)(qt * 64 + wid * 16) * E_DIM;
#pragma unroll
        for (int r = 0; r < 4; r++) {
            float linv = 1.f / __shfl(l_i, lg * 4 + r);
#pragma unroll
            for (int nf = 0; nf < 4; nf++)
                Ob[(size_t)(lg * 4 + r) * E_DIM + nf * 16 + l15] =
                    f2bf(acc_o[nf][r] * linv);
        }
    }
}

extern "C" void kernel_launch(void* const* d_in, const int* in_sizes, int n_in,
                              void* d_out, int out_size, void* d_ws, size_t ws_size,
                              hipStream_t stream) {
    (void)in_sizes; (void)n_in; (void)out_size; (void)ws_size;
    const float* x  = (const float*)d_in[0];
    const float* Wq = (const float*)d_in[1];
    const float* Wk = (const float*)d_in[2];
    const float* Wv = (const float*)d_in[3];
    const float* Wo = (const float*)d_in[4];

    unsigned short* us = (unsigned short*)d_ws;
    unsigned short* xb    = us;                  // 4096x1024
    unsigned short* WqkvT = us + 4194304;        // 3072x1024 (Wq;Wk;Wv rows)
    unsigned short* WoT   = us + 7340032;        // 1024x1024
    unsigned short* Qb    = us + 8388608;        // 4096x1024 (roped, *scale*log2e)
    unsigned short* Kb    = us + 12582912;       // 4096x1024 (roped)
    unsigned short* Vt    = us + 16777216;       // [b][h][d][s] = [2][16][64][2048]
    unsigned short* AO    = us + 20971520;
    float* cosT = (float*)((char*)d_ws + 50331648);
    float* sinT = cosT + 65536;

    k_convert<<<2048, 256, 0, stream>>>(x, xb);
    k_transw<<<dim3(32, 32, 4), dim3(32, 8), 0, stream>>>(
        Wq, Wk, Wv, Wo, WqkvT, WqkvT + 1048576, WqkvT + 2097152, WoT);
    k_rope_table<<<256, 256, 0, stream>>>(cosT, sinT);
    k_gemmN<128, 64, 48, true><<<dim3(48, 32), 256, 0, stream>>>(
        xb, WqkvT, Qb, Kb, Vt, nullptr, cosT, sinT);
    k_attn<<<dim3(16, 32), 256, 0, stream>>>(Qb, Kb, Vt, AO);
    k_gemmN<128, 64, 16, false><<<dim3(16, 32), 256, 0, stream>>>(
        AO, WoT, nullptr, nullptr, nullptr, (float*)d_out, cosT, sinT);
}